// Round 11
// baseline (122.989 us; speedup 1.0000x reference)
//
#include <hip/hip_runtime.h>

// ---------------------------------------------------------------------------
// TransNetSweepingExplRhs — fully folded algebra (R11):
//   h = x@W_in^T + b_in ; th = tanh(h); r1u = h + 0.1 b1
//   Q_i = I/11 - (0.01/121) W_i^T W_i ;  A1 = W1 Q1
//   M12t = W2^T W1 ; E^T = Q1 - 0.01 M12t Q1   (E = Q1 - 0.01 A1^T W2 / via Q1M12)
//   H2 = Wout W2 ;  G^T = H2 Q2   (G = Q2 W2^T Wout^T = A2^T Wout^T)
//   rcon = 0.01 b2 W2
//   b1v = 11 th + 0.1 r1u W1
//   r2u = r1u + 0.1 b2 - 0.1 b1v A1^T          (indep of b2v)
//   b2v = 10 th + rcon + b1v E + 0.1 r1u W2    (K=2048 with A=[b1v|r1u])
//   logits = r2u Wout^T - 0.1 b2v G + bout     (K=2048 with A=[r2u|b2v])
// 6 dispatches: prep -> P2(G0+Q1+Q2+M12t+H2+rcon) -> P3(b1v+A1+E+G^T)
// -> P4(r2u || b2v) -> P5(logits) -> softmax.  Batch chain depth 4 (was 6).
// K-loop: R6-proven 3-buffer counted-vmcnt(4) pipeline, rotation swizzle.
// ---------------------------------------------------------------------------

typedef short bf16x8 __attribute__((ext_vector_type(8)));
typedef float f32x4 __attribute__((ext_vector_type(4)));

#define M1 1048576

__device__ __forceinline__ unsigned short f2b(float f) {
  union { float f; unsigned int u; } v; v.f = f;
  unsigned int u = v.u;
  return (unsigned short)((u + 0x7FFFu + ((u >> 16) & 1u)) >> 16);
}
__device__ __forceinline__ float b2f(unsigned short u) {
  union { unsigned u; float f; } x; x.u = ((unsigned)u) << 16; return x.f;
}

__device__ __forceinline__ void gload16(const void* g, void* l) {
  __builtin_amdgcn_global_load_lds(
      (const __attribute__((address_space(1))) unsigned int*)g,
      (__attribute__((address_space(3))) unsigned int*)l, 16, 0, 0);
}

// C[m,n] = sum_k A[m,k]*B[n,k]; tile 64x64 at (bx,by); K = NKT*64.
// 4 waves (2x2, wave tile 32x32), BK=64, 3-buffer depth-2 pipeline,
// counted vmcnt(4) (vmcnt(0) only last phase), 8-chunk rotation swizzle.
template <int MODE, int NKT>
__device__ __forceinline__ void gemm64(
    const unsigned short* __restrict__ A, int lda,
    const unsigned short* __restrict__ B, int ldb,
    int bx, int by,
    const float* bias0, const float* bias1, const float* src0,
    const unsigned short* srcb,
    float* dstf0, float* dstf1,
    unsigned short* dstbf, int ldc,
    short (*As)[4096], short (*Bs)[4096]) {
  const int tid = threadIdx.x;
  const int lane = tid & 63;
  const int wid = tid >> 6;
  const int wr = wid >> 1;
  const int wc = wid & 1;
  const int m0 = bx * 64;
  const int n0 = by * 64;
  const int l15 = lane & 15;
  const int kb = lane >> 4;

  const int sr = tid >> 3;
  const int sg = ((tid & 7) - sr) & 7;
  const unsigned short* Asrc = A + (size_t)(m0 + sr) * lda + sg * 8;
  const unsigned short* Bsrc = B + (size_t)(n0 + sr) * ldb + sg * 8;
  const size_t a32 = (size_t)32 * lda;
  const size_t b32 = (size_t)32 * ldb;
  const int o0 = tid * 8;
  const int o1 = 2048 + tid * 8;

  f32x4 acc[2][2];
#pragma unroll
  for (int f = 0; f < 2; ++f)
#pragma unroll
    for (int g = 0; g < 2; ++g) acc[f][g] = (f32x4){0.f, 0.f, 0.f, 0.f};

#define STG(kt, buf)                                  \
  do {                                                \
    gload16(Asrc + (kt) * 64, &As[(buf)][o0]);        \
    gload16(Asrc + a32 + (kt) * 64, &As[(buf)][o1]);  \
    gload16(Bsrc + (kt) * 64, &Bs[(buf)][o0]);        \
    gload16(Bsrc + b32 + (kt) * 64, &Bs[(buf)][o1]);  \
  } while (0)

  STG(0, 0);
  STG(1, 1);

#pragma unroll
  for (int t = 0; t < NKT; ++t) {
    if (t < NKT - 1) {
      asm volatile("s_waitcnt vmcnt(4)" ::: "memory");
    } else {
      asm volatile("s_waitcnt vmcnt(0)" ::: "memory");
    }
    __builtin_amdgcn_sched_barrier(0);
    __builtin_amdgcn_s_barrier();
    __builtin_amdgcn_sched_barrier(0);
    if (t + 2 < NKT) STG(t + 2, (t + 2) % 3);
    const int cb = t % 3;
    bf16x8 av[2][2], bv[2][2];
#pragma unroll
    for (int f = 0; f < 2; ++f) {
      const int ra = wr * 32 + f * 16 + l15;
#pragma unroll
      for (int ks = 0; ks < 2; ++ks) {
        const int qa = (ks * 4 + kb + l15) & 7;
        av[f][ks] = *reinterpret_cast<const bf16x8*>(&As[cb][ra * 64 + qa * 8]);
      }
    }
#pragma unroll
    for (int g = 0; g < 2; ++g) {
      const int rb = wc * 32 + g * 16 + l15;
#pragma unroll
      for (int ks = 0; ks < 2; ++ks) {
        const int qb2 = (ks * 4 + kb + l15) & 7;
        bv[g][ks] = *reinterpret_cast<const bf16x8*>(&Bs[cb][rb * 64 + qb2 * 8]);
      }
    }
#pragma unroll
    for (int ks = 0; ks < 2; ++ks)
#pragma unroll
      for (int f = 0; f < 2; ++f)
#pragma unroll
        for (int g = 0; g < 2; ++g)
          acc[f][g] = __builtin_amdgcn_mfma_f32_16x16x32_bf16(av[f][ks], bv[g][ks], acc[f][g], 0, 0, 0);
  }
#undef STG

  // epilogue: C/D col = lane&15, row = (lane>>4)*4 + j
#pragma unroll
  for (int f = 0; f < 2; ++f) {
#pragma unroll
    for (int g = 0; g < 2; ++g) {
#pragma unroll
      for (int j = 0; j < 4; ++j) {
        int m = m0 + wr * 32 + f * 16 + kb * 4 + j;
        int n = n0 + wc * 32 + g * 16 + l15;
        size_t fidx = (size_t)m * 1024 + n;
        size_t cidx = (size_t)m * ldc + n;
        float v = acc[f][g][j];
        if (MODE == 0) {                  // plain bf16
          dstbf[cidx] = f2b(v);
        } else if (MODE == 1) {           // h-stage (G0)
          float h = v + bias0[n];
          float thv = tanhf(h);
          float r = h + 0.1f * bias1[n];
          dstf0[fidx] = r;
          dstf1[fidx] = thv;
          dstbf[cidx] = f2b(r);
        } else if (MODE == 2) {           // b1v = 11 th + 0.1 v
          dstbf[cidx] = f2b(11.0f * src0[fidx] + 0.1f * v);
        } else if (MODE == 3) {           // E^T = Q1 - 0.01 (M12t Q1)
          dstbf[cidx] = f2b(b2f(srcb[fidx]) - 0.01f * v);
        } else if (MODE == 4) {           // r2u = r1u + 0.1 b2 - 0.1 v
          dstbf[cidx] = f2b(src0[fidx] + 0.1f * bias0[n] - 0.1f * v);
        } else if (MODE == 5) {           // b2v = 10 th + rcon + v
          dstbf[cidx] = f2b(10.0f * src0[fidx] + bias1[n] + v);
        } else if (MODE == 6) {           // -0.1 G^T
          dstbf[cidx] = f2b(-0.1f * v);
        } else if (MODE == 8) {           // logits
          dstf0[fidx] = v + bias0[n];
        } else {                          // MODE 9: Q = I/11 - (0.01/121) v
          dstbf[cidx] = f2b((m == n ? (1.0f / 11.0f) : 0.0f) - (0.01f / 121.0f) * v);
        }
      }
    }
  }
}

__device__ __forceinline__ void map512(int b, int& bx, int& by) {
  bx = ((b & 7) << 2) | ((b >> 3) & 3);  // 0..31
  by = b >> 5;                           // 0..15
}
__device__ __forceinline__ void map256(int r, int& bx, int& by) {
  bx = ((r & 7) << 1) | ((r >> 3) & 1);  // 0..15
  by = (r >> 4) & 15;                    // 0..15
}

// P2: G0 (0..511) + Q1,Q2 (512..1023) + M12t=W2^T W1 (1024..1279)
//     + H2=Wout W2 (1280..1535) + rcon (1536..1539)
__global__ __launch_bounds__(256) void k_P2(
    const unsigned short* __restrict__ xb, const unsigned short* __restrict__ winb,
    const unsigned short* __restrict__ wtb1, const unsigned short* __restrict__ wtb2,
    const unsigned short* __restrict__ bcat5,
    const float* __restrict__ b_in, const float* __restrict__ b1,
    const float* __restrict__ b2,
    float* __restrict__ r1u, float* __restrict__ th,
    unsigned short* __restrict__ acat4, unsigned short* __restrict__ qb1,
    unsigned short* __restrict__ qb2, unsigned short* __restrict__ m12t,
    unsigned short* __restrict__ h2buf, float* __restrict__ rcon) {
  __shared__ short As[3][4096];
  __shared__ short Bs[3][4096];
  const int b = blockIdx.x;
  int bx, by;
  if (b < 512) {
    map512(b, bx, by);
    gemm64<1, 16>(xb, 1024, winb, 1024, bx, by, b_in, b1, nullptr, nullptr,
                  r1u, th, acat4 + 1024, 2048, As, Bs);
  } else if (b < 1024) {
    const int z = (b - 512) >> 8;
    map256((b - 512) & 255, bx, by);
    const unsigned short* wt = z ? wtb2 : wtb1;
    gemm64<9, 16>(wt, 1024, wt, 1024, bx, by, nullptr, nullptr, nullptr, nullptr,
                  nullptr, nullptr, z ? qb2 : qb1, 1024, As, Bs);
  } else if (b < 1280) {
    map256(b - 1024, bx, by);
    gemm64<0, 16>(wtb2, 1024, wtb1, 1024, bx, by, nullptr, nullptr, nullptr, nullptr,
                  nullptr, nullptr, m12t, 1024, As, Bs);
  } else if (b < 1536) {
    map256(b - 1280, bx, by);
    gemm64<0, 16>(bcat5, 2048, wtb2, 1024, bx, by, nullptr, nullptr, nullptr, nullptr,
                  nullptr, nullptr, h2buf, 1024, As, Bs);
  } else {
    // rcon[n] = 0.01 * sum_k b2[k] * W2[k,n]  (wtb2 row n contiguous)
    int n = (b - 1536) * 256 + threadIdx.x;
    const unsigned short* row = wtb2 + (size_t)n * 1024;
    float s = 0.f;
    for (int k = 0; k < 1024; k += 4) {
      ushort4 w4 = *reinterpret_cast<const ushort4*>(row + k);
      s += b2[k] * b2f(w4.x) + b2[k + 1] * b2f(w4.y) +
           b2[k + 2] * b2f(w4.z) + b2[k + 3] * b2f(w4.w);
    }
    rcon[n] = 0.01f * s;
  }
}

// P3: b1v (0..511) + A1=W1 Q1 (512..767) + E^T (768..1023) + G^T (1024..1279)
__global__ __launch_bounds__(256) void k_P3(
    const unsigned short* __restrict__ acat4, const unsigned short* __restrict__ wtb1,
    const unsigned short* __restrict__ wb1, const unsigned short* __restrict__ qb1,
    const unsigned short* __restrict__ qb2, const unsigned short* __restrict__ m12t,
    const unsigned short* __restrict__ h2buf, const float* __restrict__ th,
    unsigned short* __restrict__ acat4lo, unsigned short* __restrict__ a1b,
    unsigned short* __restrict__ bcat4, unsigned short* __restrict__ bcat5hi) {
  __shared__ short As[3][4096];
  __shared__ short Bs[3][4096];
  const int b = blockIdx.x;
  int bx, by;
  if (b < 512) {
    map512(b, bx, by);
    gemm64<2, 16>(acat4 + 1024, 2048, wtb1, 1024, bx, by, nullptr, nullptr, th,
                  nullptr, nullptr, nullptr, acat4lo, 2048, As, Bs);
  } else if (b < 768) {
    map256(b - 512, bx, by);
    gemm64<0, 16>(wb1, 1024, qb1, 1024, bx, by, nullptr, nullptr, nullptr, nullptr,
                  nullptr, nullptr, a1b, 1024, As, Bs);
  } else if (b < 1024) {
    map256(b - 768, bx, by);
    gemm64<3, 16>(m12t, 1024, qb1, 1024, bx, by, nullptr, nullptr, nullptr, qb1,
                  nullptr, nullptr, bcat4, 2048, As, Bs);
  } else {
    map256(b - 1024, bx, by);
    gemm64<6, 16>(h2buf, 1024, qb2, 1024, bx, by, nullptr, nullptr, nullptr, nullptr,
                  nullptr, nullptr, bcat5hi, 2048, As, Bs);
  }
}

// P4: r2u (0..511, K=1024) + b2v (512..1023, K=2048)
__global__ __launch_bounds__(256) void k_P4(
    const unsigned short* __restrict__ acat4, const unsigned short* __restrict__ a1b,
    const unsigned short* __restrict__ bcat4,
    const float* __restrict__ b2, const float* __restrict__ r1u,
    const float* __restrict__ th, const float* __restrict__ rcon,
    unsigned short* __restrict__ acat5) {
  __shared__ short As[3][4096];
  __shared__ short Bs[3][4096];
  const int b = blockIdx.x;
  int bx, by;
  if (b < 512) {
    map512(b, bx, by);
    gemm64<4, 16>(acat4, 2048, a1b, 1024, bx, by, b2, nullptr, r1u, nullptr,
                  nullptr, nullptr, acat5, 2048, As, Bs);
  } else {
    map512(b - 512, bx, by);
    gemm64<5, 32>(acat4, 2048, bcat4, 2048, bx, by, nullptr, rcon, th, nullptr,
                  nullptr, nullptr, acat5 + 1024, 2048, As, Bs);
  }
}

// P5: logits = [r2u|b2v] @ [Wout^T | -0.1 G^T] + bout  (K=2048)
__global__ __launch_bounds__(256) void k_P5(
    const unsigned short* __restrict__ acat5, const unsigned short* __restrict__ bcat5,
    const float* __restrict__ boutp, float* __restrict__ lgts) {
  __shared__ short As[3][4096];
  __shared__ short Bs[3][4096];
  int bx, by;
  map512(blockIdx.x, bx, by);
  gemm64<8, 32>(acat5, 2048, bcat5, 2048, bx, by, boutp, nullptr, nullptr, nullptr,
                lgts, nullptr, nullptr, 1024, As, Bs);
}

// prep: W1 (0..1023: wb1+wtb1), W2 (1024..2047: wtb2 + 0.1W2^T->bcat4 hi),
// x (2048..4095), W_in (4096..5119), Wout->bcat5 lo (5120..6143), b_out (6144)
__global__ __launch_bounds__(256) void k_prep(
    const float* __restrict__ x, const float* __restrict__ Win,
    const float* __restrict__ W1, const float* __restrict__ W2,
    const float* __restrict__ Wout, const float* __restrict__ bout,
    unsigned short* __restrict__ xb, unsigned short* __restrict__ winb,
    unsigned short* __restrict__ wb1, unsigned short* __restrict__ wtb1,
    unsigned short* __restrict__ wtb2, unsigned short* __restrict__ bcat4,
    unsigned short* __restrict__ bcat5, float* __restrict__ boutp) {
  __shared__ float tile[32][33];
  const int b = blockIdx.x;
  const int tid = threadIdx.x;
  if (b < 2048) {
    const int isW2 = (b >> 10) & 1;
    const float* W = isW2 ? W2 : W1;
    const int rem = b & 1023;
    const int tbx = rem & 31, tby = rem >> 5;
    const int tx = tid & 31, ty = tid >> 5;
#pragma unroll
    for (int i = ty; i < 32; i += 8) {
      float v = W[(size_t)(tby * 32 + i) * 1024 + tbx * 32 + tx];
      tile[i][tx] = v;
      if (!isW2) wb1[(size_t)(tby * 32 + i) * 1024 + tbx * 32 + tx] = f2b(v);
    }
    __syncthreads();
#pragma unroll
    for (int i = ty; i < 32; i += 8) {
      float vt = tile[tx][i];
      int rr = tbx * 32 + i, cc = tby * 32 + tx;
      if (isW2) {
        wtb2[(size_t)rr * 1024 + cc] = f2b(vt);
        bcat4[(size_t)rr * 2048 + 1024 + cc] = f2b(0.1f * vt);
      } else {
        wtb1[(size_t)rr * 1024 + cc] = f2b(vt);
      }
    }
  } else if (b < 4096) {
    int i = (b - 2048) * 256 + tid;
    float4 v = ((const float4*)x)[i];
    ((ushort4*)xb)[i] = (ushort4){f2b(v.x), f2b(v.y), f2b(v.z), f2b(v.w)};
  } else if (b < 5120) {
    int i = (b - 4096) * 256 + tid;
    float4 v = ((const float4*)Win)[i];
    ((ushort4*)winb)[i] = (ushort4){f2b(v.x), f2b(v.y), f2b(v.z), f2b(v.w)};
  } else if (b < 6144) {
    int i = (b - 5120) * 256 + tid;   // float4 index into 1024x1024
    int row = i >> 8, c4 = i & 255;
    ushort4 o = (ushort4){0, 0, 0, 0};
    if (row < 1000) {
      float4 v = ((const float4*)Wout)[i];
      o = (ushort4){f2b(v.x), f2b(v.y), f2b(v.z), f2b(v.w)};
    }
    ((ushort4*)bcat5)[(size_t)row * 512 + c4] = o;  // bcat5 lo (ld 2048)
  } else {
    for (int j = tid; j < 1024; j += 256) boutp[j] = (j < 1000) ? bout[j] : 0.0f;
  }
}

// row softmax over first 1000 cols of 2048x1024 logits -> 2048x1000
__global__ __launch_bounds__(256) void k_softmax(const float* __restrict__ lg,
                                                 float* __restrict__ out) {
  const int r = blockIdx.x;
  const float* p = lg + (size_t)r * 1024;
  float* q = out + (size_t)r * 1000;
  const int tid = threadIdx.x;
  const int lane = tid & 63;
  const int w = tid >> 6;
  __shared__ float redm[4];
  __shared__ float reds[4];
  float m = -3.0e38f;
  for (int i = tid; i < 1000; i += 256) m = fmaxf(m, p[i]);
#pragma unroll
  for (int o = 32; o > 0; o >>= 1) m = fmaxf(m, __shfl_xor(m, o));
  if (lane == 0) redm[w] = m;
  __syncthreads();
  m = fmaxf(fmaxf(redm[0], redm[1]), fmaxf(redm[2], redm[3]));
  float s = 0.0f;
  for (int i = tid; i < 1000; i += 256) {
    float e = __expf(p[i] - m);
    q[i] = e;
    s += e;
  }
#pragma unroll
  for (int o = 32; o > 0; o >>= 1) s += __shfl_xor(s, o);
  if (lane == 0) reds[w] = s;
  __syncthreads();
  float inv = 1.0f / (reds[0] + reds[1] + reds[2] + reds[3]);
  for (int i = tid; i < 1000; i += 256) q[i] *= inv;
}

extern "C" void kernel_launch(void* const* d_in, const int* in_sizes, int n_in,
                              void* d_out, int out_size, void* d_ws, size_t ws_size,
                              hipStream_t stream) {
  const float* x = (const float*)d_in[0];
  const float* W_in = (const float*)d_in[1];
  const float* b_in = (const float*)d_in[2];
  const float* W1 = (const float*)d_in[3];
  const float* b1 = (const float*)d_in[4];
  const float* W2 = (const float*)d_in[5];
  const float* b2 = (const float*)d_in[6];
  const float* W_out = (const float*)d_in[7];
  const float* b_out = (const float*)d_in[8];
  float* out = (float*)d_out;

  const size_t Bm = 2048, U = 1024;
  char* ws = (char*)d_ws;
  size_t off = 0;
  auto alloc = [&](size_t bytes) -> void* {
    void* p = ws + off;
    off += (bytes + 255) & ~(size_t)255;
    return p;
  };
  unsigned short* xb = (unsigned short*)alloc(Bm * U * 2);
  unsigned short* winb = (unsigned short*)alloc((size_t)M1 * 2);
  unsigned short* wb1 = (unsigned short*)alloc((size_t)M1 * 2);
  unsigned short* wtb1 = (unsigned short*)alloc((size_t)M1 * 2);
  unsigned short* wtb2 = (unsigned short*)alloc((size_t)M1 * 2);
  unsigned short* qb1 = (unsigned short*)alloc((size_t)M1 * 2);
  unsigned short* qb2 = (unsigned short*)alloc((size_t)M1 * 2);
  unsigned short* m12t = (unsigned short*)alloc((size_t)M1 * 2);
  unsigned short* h2buf = (unsigned short*)alloc((size_t)M1 * 2);
  unsigned short* a1b = (unsigned short*)alloc((size_t)M1 * 2);
  unsigned short* acat4 = (unsigned short*)alloc(Bm * 2 * U * 2);  // [b1v | r1u]
  unsigned short* bcat4 = (unsigned short*)alloc(2 * (size_t)M1 * 2);  // [E^T | 0.1W2^T]
  unsigned short* acat5 = (unsigned short*)alloc(Bm * 2 * U * 2);  // [r2u | b2v]
  unsigned short* bcat5 = (unsigned short*)alloc(2 * (size_t)M1 * 2);  // [Wout | -0.1G^T]
  float* boutp = (float*)alloc(U * 4);
  float* rcon = (float*)alloc(U * 4);
  float* r1u = (float*)alloc(Bm * U * 4);
  float* th = (float*)alloc(Bm * U * 4);
  float* lgts = (float*)alloc(Bm * U * 4);

  k_prep<<<6145, 256, 0, stream>>>(x, W_in, W1, W2, W_out, b_out,
                                   xb, winb, wb1, wtb1, wtb2, bcat4, bcat5, boutp);
  k_P2<<<1540, 256, 0, stream>>>(xb, winb, wtb1, wtb2, bcat5, b_in, b1, b2,
                                 r1u, th, acat4, qb1, qb2, m12t, h2buf, rcon);
  k_P3<<<1280, 256, 0, stream>>>(acat4, wtb1, wb1, qb1, qb2, m12t, h2buf, th,
                                 acat4, a1b, bcat4, bcat5 + 1024);
  k_P4<<<1024, 256, 0, stream>>>(acat4, a1b, bcat4, b2, r1u, th, rcon, acat5);
  k_P5<<<512, 256, 0, stream>>>(acat5, bcat5, boutp, lgts);
  k_softmax<<<2048, 256, 0, stream>>>(lgts, out);
}

// Round 12
// 106.869 us; speedup vs baseline: 1.1508x; 1.1508x over previous
//
#include <hip/hip_runtime.h>

// ---------------------------------------------------------------------------
// TransNetSweepingExplRhs — R12 = R10 DAG (kt-unit minimal) + superphase K-loop.
//   h = x@W_in^T + b_in ; th = tanh(h); r1u = h + 0.1 b1
//   Q_i = I/11 - (0.01/121) W_i^T W_i   (symmetric);  A_i = W_i@Q_i
//   b1v = 11 th + 0.1 (r1u@W1)
//   r2u = r1u + 0.1 b2 - 0.1 NT(b1v, A1)
//   b2v = 10 th + [b1v | 0.1 r2u] @ [Q1 ; W2^T]   (K=2048)
//   y2u = r2u - 0.1 NT(b2v, A2)
//   logits = NT(y2u, Wout) + bout ; out = softmax
// K-loop: 4 LDS buffers (double-buffered PAIRS), ONE barrier + one vmcnt(0)
// per 2 k-tiles; the vmcnt waits on loads issued a full superphase earlier
// (latency-covered); STG issued AFTER the barrier targets the pair freed by
// that barrier (race-safe). Barriers/block: 16 -> 9. Same MFMA order ->
// bit-identical output. LDS 64KB (2 blocks/CU).
// ---------------------------------------------------------------------------

typedef short bf16x8 __attribute__((ext_vector_type(8)));
typedef float f32x4 __attribute__((ext_vector_type(4)));

#define M1 1048576

__device__ __forceinline__ unsigned short f2b(float f) {
  union { float f; unsigned int u; } v; v.f = f;
  unsigned int u = v.u;
  return (unsigned short)((u + 0x7FFFu + ((u >> 16) & 1u)) >> 16);
}

__device__ __forceinline__ void gload16(const void* g, void* l) {
  __builtin_amdgcn_global_load_lds(
      (const __attribute__((address_space(1))) unsigned int*)g,
      (__attribute__((address_space(3))) unsigned int*)l, 16, 0, 0);
}

// C[m,n] = sum_k A[m,k]*B[n,k]; tile 64x64 at (bx,by); K = NKT*64, NKT even.
// 4 waves (2x2, wave tile 32x32), BK=64 per kt, superphase = 2 kt.
// 8-chunk rotation swizzle (pre-swizzled gload source + swizzled ds_read).
template <int MODE, int NKT>
__device__ __forceinline__ void gemm64(
    const unsigned short* __restrict__ A, int lda,
    const unsigned short* __restrict__ B, int ldb,
    int bx, int by,
    const float* bias0, const float* bias1, const float* src0,
    float* dstf0, float* dstf1,
    unsigned short* dstbf, int ldc, unsigned short* dstbf2,
    short (*As)[4096], short (*Bs)[4096]) {
  const int tid = threadIdx.x;
  const int lane = tid & 63;
  const int wid = tid >> 6;
  const int wr = wid >> 1;
  const int wc = wid & 1;
  const int m0 = bx * 64;
  const int n0 = by * 64;
  const int l15 = lane & 15;
  const int kb = lane >> 4;

  const int sr = tid >> 3;
  const int sg = ((tid & 7) - sr) & 7;
  const unsigned short* Asrc = A + (size_t)(m0 + sr) * lda + sg * 8;
  const unsigned short* Bsrc = B + (size_t)(n0 + sr) * ldb + sg * 8;
  const size_t a32 = (size_t)32 * lda;
  const size_t b32 = (size_t)32 * ldb;
  const int o0 = tid * 8;
  const int o1 = 2048 + tid * 8;

  f32x4 acc[2][2];
#pragma unroll
  for (int f = 0; f < 2; ++f)
#pragma unroll
    for (int g = 0; g < 2; ++g) acc[f][g] = (f32x4){0.f, 0.f, 0.f, 0.f};

#define STG(kt, buf)                                  \
  do {                                                \
    gload16(Asrc + (kt) * 64, &As[(buf)][o0]);        \
    gload16(Asrc + a32 + (kt) * 64, &As[(buf)][o1]);  \
    gload16(Bsrc + (kt) * 64, &Bs[(buf)][o0]);        \
    gload16(Bsrc + b32 + (kt) * 64, &Bs[(buf)][o1]);  \
  } while (0)

#define CMP(kt)                                                                \
  do {                                                                         \
    const int cb = (kt) & 3;                                                   \
    bf16x8 av[2][2], bv[2][2];                                                 \
    _Pragma("unroll") for (int f = 0; f < 2; ++f) {                            \
      const int ra = wr * 32 + f * 16 + l15;                                   \
      _Pragma("unroll") for (int ks = 0; ks < 2; ++ks) {                       \
        const int qa = (ks * 4 + kb + l15) & 7;                                \
        av[f][ks] = *reinterpret_cast<const bf16x8*>(&As[cb][ra * 64 + qa * 8]); \
      }                                                                        \
    }                                                                          \
    _Pragma("unroll") for (int g = 0; g < 2; ++g) {                            \
      const int rb = wc * 32 + g * 16 + l15;                                   \
      _Pragma("unroll") for (int ks = 0; ks < 2; ++ks) {                       \
        const int qb2 = (ks * 4 + kb + l15) & 7;                               \
        bv[g][ks] = *reinterpret_cast<const bf16x8*>(&Bs[cb][rb * 64 + qb2 * 8]); \
      }                                                                        \
    }                                                                          \
    _Pragma("unroll") for (int ks = 0; ks < 2; ++ks)                           \
        _Pragma("unroll") for (int f = 0; f < 2; ++f)                          \
            _Pragma("unroll") for (int g = 0; g < 2; ++g)                      \
                acc[f][g] = __builtin_amdgcn_mfma_f32_16x16x32_bf16(           \
                    av[f][ks], bv[g][ks], acc[f][g], 0, 0, 0);                 \
  } while (0)

  // prologue: stage pair 0 only (kt 0,1)
  STG(0, 0);
  STG(1, 1);

#pragma unroll
  for (int s = 0; s < NKT / 2; ++s) {
    const int k0 = 2 * s;
    // wait for pair-s loads (issued one superphase ago; covered in steady state)
    asm volatile("s_waitcnt vmcnt(0)" ::: "memory");
    __builtin_amdgcn_sched_barrier(0);
    __builtin_amdgcn_s_barrier();
    __builtin_amdgcn_sched_barrier(0);
    // stage next pair into the pair-buffers freed by this barrier
    if (k0 + 2 < NKT) STG(k0 + 2, (k0 + 2) & 3);
    if (k0 + 3 < NKT) STG(k0 + 3, (k0 + 3) & 3);
    CMP(k0);
    CMP(k0 + 1);
  }
#undef STG
#undef CMP

  // epilogue: C/D col = lane&15, row = (lane>>4)*4 + j
#pragma unroll
  for (int f = 0; f < 2; ++f) {
#pragma unroll
    for (int g = 0; g < 2; ++g) {
#pragma unroll
      for (int j = 0; j < 4; ++j) {
        int m = m0 + wr * 32 + f * 16 + kb * 4 + j;
        int n = n0 + wc * 32 + g * 16 + l15;
        size_t fidx = (size_t)m * 1024 + n;
        size_t cidx = (size_t)m * ldc + n;
        float v = acc[f][g][j];
        if (MODE == 0) {                  // plain bf16 (A1/A2)
          dstbf[cidx] = f2b(v);
        } else if (MODE == 1) {           // h-stage
          float h = v + bias0[n];
          float thv = tanhf(h);
          float r = h + 0.1f * bias1[n];
          dstf0[fidx] = r;
          dstf1[fidx] = thv;
          dstbf[cidx] = f2b(r);
        } else if (MODE == 2) {           // b1v = 11 th + 0.1 c1 -> zcat lo
          dstbf[cidx] = f2b(11.0f * src0[fidx] + 0.1f * v);
        } else if (MODE == 4) {           // r2u; store 0.1*r2u bf16 -> zcat hi
          float r = src0[fidx] + 0.1f * bias0[n] - 0.1f * v;
          dstf0[fidx] = r;
          dstbf[cidx] = f2b(0.1f * r);
        } else if (MODE == 5) {           // b2v = 10 th + v
          dstbf[cidx] = f2b(10.0f * src0[fidx] + v);
        } else if (MODE == 7) {           // y2u = r2u - 0.1 v
          dstbf[cidx] = f2b(src0[fidx] - 0.1f * v);
        } else if (MODE == 8) {           // logits
          dstf0[fidx] = v + bias0[n];
        } else {                          // MODE 9: Q = I/11 - (0.01/121) P
          float q = (m == n ? (1.0f / 11.0f) : 0.0f) - (0.01f / 121.0f) * v;
          unsigned short qq = f2b(q);
          dstbf[cidx] = qq;
          if (dstbf2) dstbf2[(size_t)m * 2048 + n] = qq;  // bcat lo (Q1)
        }
      }
    }
  }
}

__device__ __forceinline__ void map512(int b, int& bx, int& by) {
  bx = ((b & 7) << 2) | ((b >> 3) & 3);  // 0..31
  by = b >> 5;                           // 0..15
}
__device__ __forceinline__ void map256(int r, int& bx, int& by) {
  bx = ((r & 7) << 1) | ((r >> 3) & 1);  // 0..15
  by = (r >> 4) & 15;                    // 0..15
}

// D2: G0 (h-stage, blocks 0..511) + QG (Q1,Q2, blocks 512..1023)
__global__ __launch_bounds__(256) void k_D2(
    const unsigned short* __restrict__ xb, const unsigned short* __restrict__ winb,
    const unsigned short* __restrict__ wtb,
    const float* __restrict__ b_in, const float* __restrict__ b1,
    float* __restrict__ r1u, float* __restrict__ th,
    unsigned short* __restrict__ zb0, unsigned short* __restrict__ qb,
    unsigned short* __restrict__ bcat) {
  __shared__ short As[4][4096];
  __shared__ short Bs[4][4096];
  const int b = blockIdx.x;
  int bx, by;
  if (b < 512) {
    map512(b, bx, by);
    gemm64<1, 16>(xb, 1024, winb, 1024, bx, by, b_in, b1, nullptr,
                  r1u, th, zb0, 1024, nullptr, As, Bs);
  } else {
    int r = b - 512;
    const int z = r >> 8;
    map256(r & 255, bx, by);
    const unsigned short* wt = wtb + (size_t)z * M1;
    gemm64<9, 16>(wt, 1024, wt, 1024, bx, by, nullptr, nullptr, nullptr,
                  nullptr, nullptr, qb + (size_t)z * M1, 1024,
                  z == 0 ? bcat : nullptr, As, Bs);
  }
}

// D3: A1 (0..255), A2 (256..511), G1/b1v (512..1023)
__global__ __launch_bounds__(256) void k_D3(
    const unsigned short* __restrict__ wb, const unsigned short* __restrict__ qb,
    const unsigned short* __restrict__ zb0, const unsigned short* __restrict__ wtb,
    const float* __restrict__ th,
    unsigned short* __restrict__ a1b, unsigned short* __restrict__ a2b,
    unsigned short* __restrict__ zcat) {
  __shared__ short As[4][4096];
  __shared__ short Bs[4][4096];
  const int b = blockIdx.x;
  int bx, by;
  if (b < 512) {
    const int z = b >> 8;
    map256(b & 255, bx, by);
    gemm64<0, 16>(wb + (size_t)z * M1, 1024, qb + (size_t)z * M1, 1024, bx, by,
                  nullptr, nullptr, nullptr, nullptr, nullptr,
                  z == 0 ? a1b : a2b, 1024, nullptr, As, Bs);
  } else {
    map512(b - 512, bx, by);
    gemm64<2, 16>(zb0, 1024, wtb, 1024, bx, by, nullptr, nullptr, th,
                  nullptr, nullptr, zcat, 2048, nullptr, As, Bs);
  }
}

// D4: r2u = r1u + 0.1 b2 - 0.1 NT(b1v, A1)
__global__ __launch_bounds__(256) void k_D4(
    const unsigned short* __restrict__ zcat, const unsigned short* __restrict__ a1b,
    const float* __restrict__ b2, const float* __restrict__ r1u,
    float* __restrict__ r2u, unsigned short* __restrict__ zcat_hi) {
  __shared__ short As[4][4096];
  __shared__ short Bs[4][4096];
  int bx, by;
  map512(blockIdx.x, bx, by);
  gemm64<4, 16>(zcat, 2048, a1b, 1024, bx, by, b2, nullptr, r1u,
                r2u, nullptr, zcat_hi, 2048, nullptr, As, Bs);
}

// D5: b2v = 10 th + [b1v | 0.1 r2u] @ bcat  (K=2048)
__global__ __launch_bounds__(256) void k_D5(
    const unsigned short* __restrict__ zcat, const unsigned short* __restrict__ bcat,
    const float* __restrict__ th, unsigned short* __restrict__ zb2) {
  __shared__ short As[4][4096];
  __shared__ short Bs[4][4096];
  int bx, by;
  map512(blockIdx.x, bx, by);
  gemm64<5, 32>(zcat, 2048, bcat, 2048, bx, by, nullptr, nullptr, th,
                nullptr, nullptr, zb2, 1024, nullptr, As, Bs);
}

// D6: y2u = r2u - 0.1 NT(b2v, A2)
__global__ __launch_bounds__(256) void k_D6(
    const unsigned short* __restrict__ zb2, const unsigned short* __restrict__ a2b,
    const float* __restrict__ r2u, unsigned short* __restrict__ zb3) {
  __shared__ short As[4][4096];
  __shared__ short Bs[4][4096];
  int bx, by;
  map512(blockIdx.x, bx, by);
  gemm64<7, 16>(zb2, 1024, a2b, 1024, bx, by, nullptr, nullptr, r2u,
                nullptr, nullptr, zb3, 1024, nullptr, As, Bs);
}

// D7: logits = NT(y2u, Wout_pad) + bout
__global__ __launch_bounds__(256) void k_D7(
    const unsigned short* __restrict__ zb3, const unsigned short* __restrict__ woutb,
    const float* __restrict__ boutp, float* __restrict__ lgts) {
  __shared__ short As[4][4096];
  __shared__ short Bs[4][4096];
  int bx, by;
  map512(blockIdx.x, bx, by);
  gemm64<8, 16>(zb3, 1024, woutb, 1024, bx, by, boutp, nullptr, nullptr,
                lgts, nullptr, nullptr, 1024, nullptr, As, Bs);
}

// prep: W1/W2 bf16+transpose (0..2047; W2 also fills bcat hi), x (2048..4095),
// W_in (4096..5119), W_out padded (5120..6143), b_out (6144)
__global__ __launch_bounds__(256) void k_prep(
    const float* __restrict__ x, const float* __restrict__ Win,
    const float* __restrict__ W1, const float* __restrict__ W2,
    const float* __restrict__ Wout, const float* __restrict__ bout,
    unsigned short* __restrict__ xb, unsigned short* __restrict__ winb,
    unsigned short* __restrict__ wb, unsigned short* __restrict__ wtb,
    unsigned short* __restrict__ woutb, float* __restrict__ boutp,
    unsigned short* __restrict__ bcat) {
  __shared__ float tile[32][33];
  const int b = blockIdx.x;
  const int tid = threadIdx.x;
  if (b < 2048) {
    const int isW2 = (b >> 10) & 1;
    const float* W = isW2 ? W2 : W1;
    unsigned short* Wb = wb + ((size_t)isW2 << 20);
    unsigned short* WTb = wtb + ((size_t)isW2 << 20);
    const int rem = b & 1023;
    const int tbx = rem & 31, tby = rem >> 5;
    const int tx = tid & 31, ty = tid >> 5;
#pragma unroll
    for (int i = ty; i < 32; i += 8) {
      float v = W[(size_t)(tby * 32 + i) * 1024 + tbx * 32 + tx];
      tile[i][tx] = v;
      Wb[(size_t)(tby * 32 + i) * 1024 + tbx * 32 + tx] = f2b(v);
    }
    __syncthreads();
#pragma unroll
    for (int i = ty; i < 32; i += 8) {
      unsigned short t2 = f2b(tile[tx][i]);
      int rr = tbx * 32 + i, cc = tby * 32 + tx;
      WTb[(size_t)rr * 1024 + cc] = t2;
      if (isW2) bcat[(size_t)rr * 2048 + 1024 + cc] = t2;  // bcat hi = W2^T
    }
  } else if (b < 4096) {
    int i = (b - 2048) * 256 + tid;
    float4 v = ((const float4*)x)[i];
    ((ushort4*)xb)[i] = (ushort4){f2b(v.x), f2b(v.y), f2b(v.z), f2b(v.w)};
  } else if (b < 5120) {
    int i = (b - 4096) * 256 + tid;
    float4 v = ((const float4*)Win)[i];
    ((ushort4*)winb)[i] = (ushort4){f2b(v.x), f2b(v.y), f2b(v.z), f2b(v.w)};
  } else if (b < 6144) {
    int i = (b - 5120) * 256 + tid;
    ushort4 o = (ushort4){0, 0, 0, 0};
    if ((i >> 8) < 1000) {
      float4 v = ((const float4*)Wout)[i];
      o = (ushort4){f2b(v.x), f2b(v.y), f2b(v.z), f2b(v.w)};
    }
    ((ushort4*)woutb)[i] = o;
  } else {
    for (int j = tid; j < 1024; j += 256) boutp[j] = (j < 1000) ? bout[j] : 0.0f;
  }
}

// row softmax over first 1000 cols of 2048x1024 logits -> 2048x1000
__global__ __launch_bounds__(256) void k_softmax(const float* __restrict__ lg,
                                                 float* __restrict__ out) {
  const int r = blockIdx.x;
  const float4* p4 = (const float4*)(lg + (size_t)r * 1024);
  float* q = out + (size_t)r * 1000;
  const int tid = threadIdx.x;
  const int lane = tid & 63;
  const int w = tid >> 6;
  __shared__ float redm[4];
  __shared__ float reds[4];
  float m = -3.0e38f;
  for (int i = tid; i < 250; i += 256) {
    float4 v = p4[i];
    m = fmaxf(fmaxf(fmaxf(m, v.x), fmaxf(v.y, v.z)), v.w);
  }
#pragma unroll
  for (int o = 32; o > 0; o >>= 1) m = fmaxf(m, __shfl_xor(m, o));
  if (lane == 0) redm[w] = m;
  __syncthreads();
  m = fmaxf(fmaxf(redm[0], redm[1]), fmaxf(redm[2], redm[3]));
  float s = 0.0f;
  for (int i = tid; i < 250; i += 256) {
    float4 v = p4[i];
    float e0 = __expf(v.x - m), e1 = __expf(v.y - m);
    float e2 = __expf(v.z - m), e3 = __expf(v.w - m);
    float4 e = {e0, e1, e2, e3};
    *reinterpret_cast<float4*>(q + i * 4) = e;
    s += e0 + e1 + e2 + e3;
  }
#pragma unroll
  for (int o = 32; o > 0; o >>= 1) s += __shfl_xor(s, o);
  if (lane == 0) reds[w] = s;
  __syncthreads();
  float inv = 1.0f / (reds[0] + reds[1] + reds[2] + reds[3]);
  for (int i = tid; i < 250; i += 256) {
    float4 e = *reinterpret_cast<const float4*>(q + i * 4);
    e.x *= inv; e.y *= inv; e.z *= inv; e.w *= inv;
    *reinterpret_cast<float4*>(q + i * 4) = e;
  }
}

extern "C" void kernel_launch(void* const* d_in, const int* in_sizes, int n_in,
                              void* d_out, int out_size, void* d_ws, size_t ws_size,
                              hipStream_t stream) {
  const float* x = (const float*)d_in[0];
  const float* W_in = (const float*)d_in[1];
  const float* b_in = (const float*)d_in[2];
  const float* W1 = (const float*)d_in[3];
  const float* b1 = (const float*)d_in[4];
  const float* W2 = (const float*)d_in[5];
  const float* b2 = (const float*)d_in[6];
  const float* W_out = (const float*)d_in[7];
  const float* b_out = (const float*)d_in[8];
  float* out = (float*)d_out;

  const size_t Bm = 2048, U = 1024;
  char* ws = (char*)d_ws;
  size_t off = 0;
  auto alloc = [&](size_t bytes) -> void* {
    void* p = ws + off;
    off += (bytes + 255) & ~(size_t)255;
    return p;
  };
  unsigned short* xb = (unsigned short*)alloc(Bm * U * 2);
  unsigned short* winb = (unsigned short*)alloc((size_t)M1 * 2);
  unsigned short* wb = (unsigned short*)alloc(2 * (size_t)M1 * 2);    // W1,W2
  unsigned short* wtb = (unsigned short*)alloc(2 * (size_t)M1 * 2);   // W1^T,W2^T
  unsigned short* qb = (unsigned short*)alloc(2 * (size_t)M1 * 2);    // Q1,Q2
  unsigned short* a1b = (unsigned short*)alloc((size_t)M1 * 2);       // W1@Q1
  unsigned short* a2b = (unsigned short*)alloc((size_t)M1 * 2);       // W2@Q2
  unsigned short* bcat = (unsigned short*)alloc(2 * (size_t)M1 * 2);  // [Q1 ; W2^T] 1024x2048
  unsigned short* woutb = (unsigned short*)alloc((size_t)M1 * 2);
  float* boutp = (float*)alloc(U * 4);
  unsigned short* zb0 = (unsigned short*)alloc(Bm * U * 2);           // r1u bf16
  unsigned short* zcat = (unsigned short*)alloc(Bm * 2 * U * 2);      // [b1v | 0.1 r2u]
  unsigned short* zb2 = (unsigned short*)alloc(Bm * U * 2);           // b2v
  unsigned short* zb3 = (unsigned short*)alloc(Bm * U * 2);           // y2u
  float* r1u = (float*)alloc(Bm * U * 4);
  float* th = (float*)alloc(Bm * U * 4);
  float* r2u = (float*)alloc(Bm * U * 4);
  float* lgts = (float*)alloc(Bm * U * 4);

  k_prep<<<6145, 256, 0, stream>>>(x, W_in, W1, W2, W_out, b_out,
                                   xb, winb, wb, wtb, woutb, boutp, bcat);
  k_D2<<<1024, 256, 0, stream>>>(xb, winb, wtb, b_in, b1, r1u, th, zb0, qb, bcat);
  k_D3<<<1024, 256, 0, stream>>>(wb, qb, zb0, wtb, th, a1b, a2b, zcat);
  k_D4<<<512, 256, 0, stream>>>(zcat, a1b, b2, r1u, r2u, zcat + 1024);
  k_D5<<<512, 256, 0, stream>>>(zcat, bcat, th, zb2);
  k_D6<<<512, 256, 0, stream>>>(zb2, a2b, r2u, zb3);
  k_D7<<<512, 256, 0, stream>>>(zb3, woutb, boutp, lgts);
  k_softmax<<<2048, 256, 0, stream>>>(lgts, out);
}

// Round 13
// 105.707 us; speedup vs baseline: 1.1635x; 1.0110x over previous
//
#include <hip/hip_runtime.h>

// ---------------------------------------------------------------------------
// TransNetSweepingExplRhs — R13 = R12 + T5 setprio + D5 L2-fitted XCD map.
//   h = x@W_in^T + b_in ; th = tanh(h); r1u = h + 0.1 b1
//   Q_i = I/11 - (0.01/121) W_i^T W_i   (symmetric);  A_i = W_i@Q_i
//   b1v = 11 th + 0.1 (r1u@W1)
//   r2u = r1u + 0.1 b2 - 0.1 NT(b1v, A1)
//   b2v = 10 th + [b1v | 0.1 r2u] @ [Q1 ; W2^T]   (K=2048)
//   y2u = r2u - 0.1 NT(b2v, A2)
//   logits = NT(y2u, Wout) + bout ; out = softmax
// K-loop: 4 LDS buffers (double-buffered PAIRS), one barrier + one vmcnt(0)
// per 2 k-tiles; MFMA cluster wrapped in s_setprio(1)/(0) (T5: pays when
// co-resident blocks drift out of phase — 2 unsynced blocks/CU here).
// D5 (K=2048) uses an 8bx x 8by per-XCD map (4MB footprint, L2-fit).
// ---------------------------------------------------------------------------

typedef short bf16x8 __attribute__((ext_vector_type(8)));
typedef float f32x4 __attribute__((ext_vector_type(4)));

#define M1 1048576

__device__ __forceinline__ unsigned short f2b(float f) {
  union { float f; unsigned int u; } v; v.f = f;
  unsigned int u = v.u;
  return (unsigned short)((u + 0x7FFFu + ((u >> 16) & 1u)) >> 16);
}

__device__ __forceinline__ void gload16(const void* g, void* l) {
  __builtin_amdgcn_global_load_lds(
      (const __attribute__((address_space(1))) unsigned int*)g,
      (__attribute__((address_space(3))) unsigned int*)l, 16, 0, 0);
}

// C[m,n] = sum_k A[m,k]*B[n,k]; tile 64x64 at (bx,by); K = NKT*64, NKT even.
// 4 waves (2x2, wave tile 32x32), BK=64 per kt, superphase = 2 kt.
// 8-chunk rotation swizzle (pre-swizzled gload source + swizzled ds_read).
template <int MODE, int NKT>
__device__ __forceinline__ void gemm64(
    const unsigned short* __restrict__ A, int lda,
    const unsigned short* __restrict__ B, int ldb,
    int bx, int by,
    const float* bias0, const float* bias1, const float* src0,
    float* dstf0, float* dstf1,
    unsigned short* dstbf, int ldc, unsigned short* dstbf2,
    short (*As)[4096], short (*Bs)[4096]) {
  const int tid = threadIdx.x;
  const int lane = tid & 63;
  const int wid = tid >> 6;
  const int wr = wid >> 1;
  const int wc = wid & 1;
  const int m0 = bx * 64;
  const int n0 = by * 64;
  const int l15 = lane & 15;
  const int kb = lane >> 4;

  const int sr = tid >> 3;
  const int sg = ((tid & 7) - sr) & 7;
  const unsigned short* Asrc = A + (size_t)(m0 + sr) * lda + sg * 8;
  const unsigned short* Bsrc = B + (size_t)(n0 + sr) * ldb + sg * 8;
  const size_t a32 = (size_t)32 * lda;
  const size_t b32 = (size_t)32 * ldb;
  const int o0 = tid * 8;
  const int o1 = 2048 + tid * 8;

  f32x4 acc[2][2];
#pragma unroll
  for (int f = 0; f < 2; ++f)
#pragma unroll
    for (int g = 0; g < 2; ++g) acc[f][g] = (f32x4){0.f, 0.f, 0.f, 0.f};

#define STG(kt, buf)                                  \
  do {                                                \
    gload16(Asrc + (kt) * 64, &As[(buf)][o0]);        \
    gload16(Asrc + a32 + (kt) * 64, &As[(buf)][o1]);  \
    gload16(Bsrc + (kt) * 64, &Bs[(buf)][o0]);        \
    gload16(Bsrc + b32 + (kt) * 64, &Bs[(buf)][o1]);  \
  } while (0)

#define CMP(kt)                                                                \
  do {                                                                         \
    const int cb = (kt) & 3;                                                   \
    bf16x8 av[2][2], bv[2][2];                                                 \
    _Pragma("unroll") for (int f = 0; f < 2; ++f) {                            \
      const int ra = wr * 32 + f * 16 + l15;                                   \
      _Pragma("unroll") for (int ks = 0; ks < 2; ++ks) {                       \
        const int qa = (ks * 4 + kb + l15) & 7;                                \
        av[f][ks] = *reinterpret_cast<const bf16x8*>(&As[cb][ra * 64 + qa * 8]); \
      }                                                                        \
    }                                                                          \
    _Pragma("unroll") for (int g = 0; g < 2; ++g) {                            \
      const int rb = wc * 32 + g * 16 + l15;                                   \
      _Pragma("unroll") for (int ks = 0; ks < 2; ++ks) {                       \
        const int qb2 = (ks * 4 + kb + l15) & 7;                               \
        bv[g][ks] = *reinterpret_cast<const bf16x8*>(&Bs[cb][rb * 64 + qb2 * 8]); \
      }                                                                        \
    }                                                                          \
    _Pragma("unroll") for (int ks = 0; ks < 2; ++ks)                           \
        _Pragma("unroll") for (int f = 0; f < 2; ++f)                          \
            _Pragma("unroll") for (int g = 0; g < 2; ++g)                      \
                acc[f][g] = __builtin_amdgcn_mfma_f32_16x16x32_bf16(           \
                    av[f][ks], bv[g][ks], acc[f][g], 0, 0, 0);                 \
  } while (0)

  // prologue: stage pair 0 only (kt 0,1)
  STG(0, 0);
  STG(1, 1);

#pragma unroll
  for (int s = 0; s < NKT / 2; ++s) {
    const int k0 = 2 * s;
    // wait for pair-s loads (issued one superphase ago; covered in steady state)
    asm volatile("s_waitcnt vmcnt(0)" ::: "memory");
    __builtin_amdgcn_sched_barrier(0);
    __builtin_amdgcn_s_barrier();
    __builtin_amdgcn_sched_barrier(0);
    // stage next pair into the pair-buffers freed by this barrier
    if (k0 + 2 < NKT) STG(k0 + 2, (k0 + 2) & 3);
    if (k0 + 3 < NKT) STG(k0 + 3, (k0 + 3) & 3);
    __builtin_amdgcn_s_setprio(1);
    CMP(k0);
    CMP(k0 + 1);
    __builtin_amdgcn_s_setprio(0);
  }
#undef STG
#undef CMP

  // epilogue: C/D col = lane&15, row = (lane>>4)*4 + j
#pragma unroll
  for (int f = 0; f < 2; ++f) {
#pragma unroll
    for (int g = 0; g < 2; ++g) {
#pragma unroll
      for (int j = 0; j < 4; ++j) {
        int m = m0 + wr * 32 + f * 16 + kb * 4 + j;
        int n = n0 + wc * 32 + g * 16 + l15;
        size_t fidx = (size_t)m * 1024 + n;
        size_t cidx = (size_t)m * ldc + n;
        float v = acc[f][g][j];
        if (MODE == 0) {                  // plain bf16 (A1/A2)
          dstbf[cidx] = f2b(v);
        } else if (MODE == 1) {           // h-stage
          float h = v + bias0[n];
          float thv = tanhf(h);
          float r = h + 0.1f * bias1[n];
          dstf0[fidx] = r;
          dstf1[fidx] = thv;
          dstbf[cidx] = f2b(r);
        } else if (MODE == 2) {           // b1v = 11 th + 0.1 c1 -> zcat lo
          dstbf[cidx] = f2b(11.0f * src0[fidx] + 0.1f * v);
        } else if (MODE == 4) {           // r2u; store 0.1*r2u bf16 -> zcat hi
          float r = src0[fidx] + 0.1f * bias0[n] - 0.1f * v;
          dstf0[fidx] = r;
          dstbf[cidx] = f2b(0.1f * r);
        } else if (MODE == 5) {           // b2v = 10 th + v
          dstbf[cidx] = f2b(10.0f * src0[fidx] + v);
        } else if (MODE == 7) {           // y2u = r2u - 0.1 v
          dstbf[cidx] = f2b(src0[fidx] - 0.1f * v);
        } else if (MODE == 8) {           // logits
          dstf0[fidx] = v + bias0[n];
        } else {                          // MODE 9: Q = I/11 - (0.01/121) P
          float q = (m == n ? (1.0f / 11.0f) : 0.0f) - (0.01f / 121.0f) * v;
          unsigned short qq = f2b(q);
          dstbf[cidx] = qq;
          if (dstbf2) dstbf2[(size_t)m * 2048 + n] = qq;  // bcat lo (Q1)
        }
      }
    }
  }
}

__device__ __forceinline__ void map512(int b, int& bx, int& by) {
  bx = ((b & 7) << 2) | ((b >> 3) & 3);  // 0..31
  by = b >> 5;                           // 0..15
}
__device__ __forceinline__ void map256(int r, int& bx, int& by) {
  bx = ((r & 7) << 1) | ((r >> 3) & 1);  // 0..15
  by = (r >> 4) & 15;                    // 0..15
}
// D5-only: 8bx x 8by per XCD -> per-XCD footprint A 2MB + B 2MB (K=2048)
__device__ __forceinline__ void map512k2(int b, int& bx, int& by) {
  const int x = b & 7;       // XCD
  const int j = b >> 3;      // 0..63
  bx = ((x & 3) << 3) | (j & 7);
  by = ((x >> 2) << 3) | (j >> 3);
}

// D2: G0 (h-stage, blocks 0..511) + QG (Q1,Q2, blocks 512..1023)
__global__ __launch_bounds__(256) void k_D2(
    const unsigned short* __restrict__ xb, const unsigned short* __restrict__ winb,
    const unsigned short* __restrict__ wtb,
    const float* __restrict__ b_in, const float* __restrict__ b1,
    float* __restrict__ r1u, float* __restrict__ th,
    unsigned short* __restrict__ zb0, unsigned short* __restrict__ qb,
    unsigned short* __restrict__ bcat) {
  __shared__ short As[4][4096];
  __shared__ short Bs[4][4096];
  const int b = blockIdx.x;
  int bx, by;
  if (b < 512) {
    map512(b, bx, by);
    gemm64<1, 16>(xb, 1024, winb, 1024, bx, by, b_in, b1, nullptr,
                  r1u, th, zb0, 1024, nullptr, As, Bs);
  } else {
    int r = b - 512;
    const int z = r >> 8;
    map256(r & 255, bx, by);
    const unsigned short* wt = wtb + (size_t)z * M1;
    gemm64<9, 16>(wt, 1024, wt, 1024, bx, by, nullptr, nullptr, nullptr,
                  nullptr, nullptr, qb + (size_t)z * M1, 1024,
                  z == 0 ? bcat : nullptr, As, Bs);
  }
}

// D3: A1 (0..255), A2 (256..511), G1/b1v (512..1023)
__global__ __launch_bounds__(256) void k_D3(
    const unsigned short* __restrict__ wb, const unsigned short* __restrict__ qb,
    const unsigned short* __restrict__ zb0, const unsigned short* __restrict__ wtb,
    const float* __restrict__ th,
    unsigned short* __restrict__ a1b, unsigned short* __restrict__ a2b,
    unsigned short* __restrict__ zcat) {
  __shared__ short As[4][4096];
  __shared__ short Bs[4][4096];
  const int b = blockIdx.x;
  int bx, by;
  if (b < 512) {
    const int z = b >> 8;
    map256(b & 255, bx, by);
    gemm64<0, 16>(wb + (size_t)z * M1, 1024, qb + (size_t)z * M1, 1024, bx, by,
                  nullptr, nullptr, nullptr, nullptr, nullptr,
                  z == 0 ? a1b : a2b, 1024, nullptr, As, Bs);
  } else {
    map512(b - 512, bx, by);
    gemm64<2, 16>(zb0, 1024, wtb, 1024, bx, by, nullptr, nullptr, th,
                  nullptr, nullptr, zcat, 2048, nullptr, As, Bs);
  }
}

// D4: r2u = r1u + 0.1 b2 - 0.1 NT(b1v, A1)
__global__ __launch_bounds__(256) void k_D4(
    const unsigned short* __restrict__ zcat, const unsigned short* __restrict__ a1b,
    const float* __restrict__ b2, const float* __restrict__ r1u,
    float* __restrict__ r2u, unsigned short* __restrict__ zcat_hi) {
  __shared__ short As[4][4096];
  __shared__ short Bs[4][4096];
  int bx, by;
  map512(blockIdx.x, bx, by);
  gemm64<4, 16>(zcat, 2048, a1b, 1024, bx, by, b2, nullptr, r1u,
                r2u, nullptr, zcat_hi, 2048, nullptr, As, Bs);
}

// D5: b2v = 10 th + [b1v | 0.1 r2u] @ bcat  (K=2048)
__global__ __launch_bounds__(256) void k_D5(
    const unsigned short* __restrict__ zcat, const unsigned short* __restrict__ bcat,
    const float* __restrict__ th, unsigned short* __restrict__ zb2) {
  __shared__ short As[4][4096];
  __shared__ short Bs[4][4096];
  int bx, by;
  map512k2(blockIdx.x, bx, by);
  gemm64<5, 32>(zcat, 2048, bcat, 2048, bx, by, nullptr, nullptr, th,
                nullptr, nullptr, zb2, 1024, nullptr, As, Bs);
}

// D6: y2u = r2u - 0.1 NT(b2v, A2)
__global__ __launch_bounds__(256) void k_D6(
    const unsigned short* __restrict__ zb2, const unsigned short* __restrict__ a2b,
    const float* __restrict__ r2u, unsigned short* __restrict__ zb3) {
  __shared__ short As[4][4096];
  __shared__ short Bs[4][4096];
  int bx, by;
  map512(blockIdx.x, bx, by);
  gemm64<7, 16>(zb2, 1024, a2b, 1024, bx, by, nullptr, nullptr, r2u,
                nullptr, nullptr, zb3, 1024, nullptr, As, Bs);
}

// D7: logits = NT(y2u, Wout_pad) + bout
__global__ __launch_bounds__(256) void k_D7(
    const unsigned short* __restrict__ zb3, const unsigned short* __restrict__ woutb,
    const float* __restrict__ boutp, float* __restrict__ lgts) {
  __shared__ short As[4][4096];
  __shared__ short Bs[4][4096];
  int bx, by;
  map512(blockIdx.x, bx, by);
  gemm64<8, 16>(zb3, 1024, woutb, 1024, bx, by, boutp, nullptr, nullptr,
                lgts, nullptr, nullptr, 1024, nullptr, As, Bs);
}

// prep: W1/W2 bf16+transpose (0..2047; W2 also fills bcat hi), x (2048..4095),
// W_in (4096..5119), W_out padded (5120..6143), b_out (6144)
__global__ __launch_bounds__(256) void k_prep(
    const float* __restrict__ x, const float* __restrict__ Win,
    const float* __restrict__ W1, const float* __restrict__ W2,
    const float* __restrict__ Wout, const float* __restrict__ bout,
    unsigned short* __restrict__ xb, unsigned short* __restrict__ winb,
    unsigned short* __restrict__ wb, unsigned short* __restrict__ wtb,
    unsigned short* __restrict__ woutb, float* __restrict__ boutp,
    unsigned short* __restrict__ bcat) {
  __shared__ float tile[32][33];
  const int b = blockIdx.x;
  const int tid = threadIdx.x;
  if (b < 2048) {
    const int isW2 = (b >> 10) & 1;
    const float* W = isW2 ? W2 : W1;
    unsigned short* Wb = wb + ((size_t)isW2 << 20);
    unsigned short* WTb = wtb + ((size_t)isW2 << 20);
    const int rem = b & 1023;
    const int tbx = rem & 31, tby = rem >> 5;
    const int tx = tid & 31, ty = tid >> 5;
#pragma unroll
    for (int i = ty; i < 32; i += 8) {
      float v = W[(size_t)(tby * 32 + i) * 1024 + tbx * 32 + tx];
      tile[i][tx] = v;
      Wb[(size_t)(tby * 32 + i) * 1024 + tbx * 32 + tx] = f2b(v);
    }
    __syncthreads();
#pragma unroll
    for (int i = ty; i < 32; i += 8) {
      unsigned short t2 = f2b(tile[tx][i]);
      int rr = tbx * 32 + i, cc = tby * 32 + tx;
      WTb[(size_t)rr * 1024 + cc] = t2;
      if (isW2) bcat[(size_t)rr * 2048 + 1024 + cc] = t2;  // bcat hi = W2^T
    }
  } else if (b < 4096) {
    int i = (b - 2048) * 256 + tid;
    float4 v = ((const float4*)x)[i];
    ((ushort4*)xb)[i] = (ushort4){f2b(v.x), f2b(v.y), f2b(v.z), f2b(v.w)};
  } else if (b < 5120) {
    int i = (b - 4096) * 256 + tid;
    float4 v = ((const float4*)Win)[i];
    ((ushort4*)winb)[i] = (ushort4){f2b(v.x), f2b(v.y), f2b(v.z), f2b(v.w)};
  } else if (b < 6144) {
    int i = (b - 5120) * 256 + tid;
    ushort4 o = (ushort4){0, 0, 0, 0};
    if ((i >> 8) < 1000) {
      float4 v = ((const float4*)Wout)[i];
      o = (ushort4){f2b(v.x), f2b(v.y), f2b(v.z), f2b(v.w)};
    }
    ((ushort4*)woutb)[i] = o;
  } else {
    for (int j = tid; j < 1024; j += 256) boutp[j] = (j < 1000) ? bout[j] : 0.0f;
  }
}

// row softmax over first 1000 cols of 2048x1024 logits -> 2048x1000
__global__ __launch_bounds__(256) void k_softmax(const float* __restrict__ lg,
                                                 float* __restrict__ out) {
  const int r = blockIdx.x;
  const float4* p4 = (const float4*)(lg + (size_t)r * 1024);
  float* q = out + (size_t)r * 1000;
  const int tid = threadIdx.x;
  const int lane = tid & 63;
  const int w = tid >> 6;
  __shared__ float redm[4];
  __shared__ float reds[4];
  float m = -3.0e38f;
  for (int i = tid; i < 250; i += 256) {
    float4 v = p4[i];
    m = fmaxf(fmaxf(fmaxf(m, v.x), fmaxf(v.y, v.z)), v.w);
  }
#pragma unroll
  for (int o = 32; o > 0; o >>= 1) m = fmaxf(m, __shfl_xor(m, o));
  if (lane == 0) redm[w] = m;
  __syncthreads();
  m = fmaxf(fmaxf(redm[0], redm[1]), fmaxf(redm[2], redm[3]));
  float s = 0.0f;
  for (int i = tid; i < 250; i += 256) {
    float4 v = p4[i];
    float e0 = __expf(v.x - m), e1 = __expf(v.y - m);
    float e2 = __expf(v.z - m), e3 = __expf(v.w - m);
    float4 e = {e0, e1, e2, e3};
    *reinterpret_cast<float4*>(q + i * 4) = e;
    s += e0 + e1 + e2 + e3;
  }
#pragma unroll
  for (int o = 32; o > 0; o >>= 1) s += __shfl_xor(s, o);
  if (lane == 0) reds[w] = s;
  __syncthreads();
  float inv = 1.0f / (reds[0] + reds[1] + reds[2] + reds[3]);
  for (int i = tid; i < 250; i += 256) {
    float4 e = *reinterpret_cast<const float4*>(q + i * 4);
    e.x *= inv; e.y *= inv; e.z *= inv; e.w *= inv;
    *reinterpret_cast<float4*>(q + i * 4) = e;
  }
}

extern "C" void kernel_launch(void* const* d_in, const int* in_sizes, int n_in,
                              void* d_out, int out_size, void* d_ws, size_t ws_size,
                              hipStream_t stream) {
  const float* x = (const float*)d_in[0];
  const float* W_in = (const float*)d_in[1];
  const float* b_in = (const float*)d_in[2];
  const float* W1 = (const float*)d_in[3];
  const float* b1 = (const float*)d_in[4];
  const float* W2 = (const float*)d_in[5];
  const float* b2 = (const float*)d_in[6];
  const float* W_out = (const float*)d_in[7];
  const float* b_out = (const float*)d_in[8];
  float* out = (float*)d_out;

  const size_t Bm = 2048, U = 1024;
  char* ws = (char*)d_ws;
  size_t off = 0;
  auto alloc = [&](size_t bytes) -> void* {
    void* p = ws + off;
    off += (bytes + 255) & ~(size_t)255;
    return p;
  };
  unsigned short* xb = (unsigned short*)alloc(Bm * U * 2);
  unsigned short* winb = (unsigned short*)alloc((size_t)M1 * 2);
  unsigned short* wb = (unsigned short*)alloc(2 * (size_t)M1 * 2);    // W1,W2
  unsigned short* wtb = (unsigned short*)alloc(2 * (size_t)M1 * 2);   // W1^T,W2^T
  unsigned short* qb = (unsigned short*)alloc(2 * (size_t)M1 * 2);    // Q1,Q2
  unsigned short* a1b = (unsigned short*)alloc((size_t)M1 * 2);       // W1@Q1
  unsigned short* a2b = (unsigned short*)alloc((size_t)M1 * 2);       // W2@Q2
  unsigned short* bcat = (unsigned short*)alloc(2 * (size_t)M1 * 2);  // [Q1 ; W2^T] 1024x2048
  unsigned short* woutb = (unsigned short*)alloc((size_t)M1 * 2);
  float* boutp = (float*)alloc(U * 4);
  unsigned short* zb0 = (unsigned short*)alloc(Bm * U * 2);           // r1u bf16
  unsigned short* zcat = (unsigned short*)alloc(Bm * 2 * U * 2);      // [b1v | 0.1 r2u]
  unsigned short* zb2 = (unsigned short*)alloc(Bm * U * 2);           // b2v
  unsigned short* zb3 = (unsigned short*)alloc(Bm * U * 2);           // y2u
  float* r1u = (float*)alloc(Bm * U * 4);
  float* th = (float*)alloc(Bm * U * 4);
  float* r2u = (float*)alloc(Bm * U * 4);
  float* lgts = (float*)alloc(Bm * U * 4);

  k_prep<<<6145, 256, 0, stream>>>(x, W_in, W1, W2, W_out, b_out,
                                   xb, winb, wb, wtb, woutb, boutp, bcat);
  k_D2<<<1024, 256, 0, stream>>>(xb, winb, wtb, b_in, b1, r1u, th, zb0, qb, bcat);
  k_D3<<<1024, 256, 0, stream>>>(wb, qb, zb0, wtb, th, a1b, a2b, zcat);
  k_D4<<<512, 256, 0, stream>>>(zcat, a1b, b2, r1u, r2u, zcat + 1024);
  k_D5<<<512, 256, 0, stream>>>(zcat, bcat, th, zb2);
  k_D6<<<512, 256, 0, stream>>>(zb2, a2b, r2u, zb3);
  k_D7<<<512, 256, 0, stream>>>(zb3, woutb, boutp, lgts);
  k_softmax<<<2048, 256, 0, stream>>>(lgts, out);
}